// Round 1
// baseline (343.786 us; speedup 1.0000x reference)
//
#include <hip/hip_runtime.h>
#include <hip/hip_bf16.h>
#include <math.h>

// ---------------- problem constants (B=1) ----------------
constexpr int NRIG = 512;
constexpr int NRES = 448;
constexpr int CS   = 384;
constexpr int CZ   = 128;
constexpr int CH   = 16;
constexpr int NH   = 12;
constexpr int PQ   = 4;
constexpr int PV   = 8;
constexpr int HC   = NH * CH;        // 192
constexpr float INF_ = 100000.0f;

// ---------------- workspace layout (floats) ----------------
constexpr size_t OFF_Q   = 0;                               // 512*192
constexpr size_t OFF_K   = OFF_Q   + (size_t)NRIG*HC;       // 512*192
constexpr size_t OFF_V   = OFF_K   + (size_t)NRIG*HC;       // 512*192
constexpr size_t OFF_QP  = OFF_V   + (size_t)NRIG*HC;       // 512*144
constexpr size_t OFF_KP  = OFF_QP  + (size_t)NRIG*NH*PQ*3;  // 512*144
constexpr size_t OFF_VP  = OFF_KP  + (size_t)NRIG*NH*PQ*3;  // 512*288
constexpr size_t OFF_PZ  = OFF_VP  + (size_t)NRIG*NH*PV*3;  // 512*32
constexpr size_t OFF_O   = OFF_PZ  + (size_t)NRIG*32;       // 512*192
constexpr size_t OFF_OPT = OFF_O   + (size_t)NRIG*HC;       // 512*288
constexpr size_t OFF_RS  = OFF_OPT + (size_t)NRIG*NH*PV*3;  // 512*12
constexpr size_t OFF_B   = OFF_RS  + (size_t)NRIG*NH;       // 12*512*512

// =====================================================================
// Kernel A: projections q/k/v, rotated q_pts/k_pts/v_pts, pz_diag
// block = 4 rigids, 256 threads. Weight reads amortized x4.
// =====================================================================
__global__ __launch_bounds__(256) void proj_kernel(
    const float* __restrict__ s, const float* __restrict__ z,
    const float* __restrict__ rot, const float* __restrict__ trans,
    const int* __restrict__ ridx,
    const float* __restrict__ wq,  const float* __restrict__ bq,
    const float* __restrict__ wkv, const float* __restrict__ bkv,
    const float* __restrict__ wqp, const float* __restrict__ bqp,
    const float* __restrict__ wkvp,const float* __restrict__ bkvp,
    const float* __restrict__ wdz, const float* __restrict__ bdz,
    float* __restrict__ ws)
{
    constexpr int TN = 4;
    __shared__ float sS[TN][CS];     // s rows
    __shared__ float sZ[TN][CZ];     // z diag rows
    __shared__ float sP[TN][576];    // raw local-frame points: qp(144) + kvp(432)
    const int n0 = blockIdx.x * TN;
    const int t  = threadIdx.x;

    for (int e = t; e < TN*CS; e += 256)
        sS[e/CS][e%CS] = s[(size_t)(n0 + e/CS)*CS + (e%CS)];
    for (int e = t; e < TN*CZ; e += 256) {
        int nn = e / CZ; int ri = ridx[n0+nn];
        sZ[nn][e%CZ] = z[((size_t)ri*NRES + ri)*CZ + (e%CZ)];
    }
    __syncthreads();

    float* q  = ws + OFF_Q;  float* k = ws + OFF_K;  float* v = ws + OFF_V;
    float* pz = ws + OFF_PZ;

    // 1152 projection outputs + 32 pz_diag outputs per rigid
    for (int o = t; o < 1184; o += 256) {
        float a0=0.f,a1=0.f,a2=0.f,a3=0.f;
        if (o < 1152) {
            const float* w; int ld;
            if (o < 192)      { w = wq   + o;       ld = HC;  }
            else if (o < 576) { w = wkv  + (o-192); ld = 384; }
            else if (o < 720) { w = wqp  + (o-576); ld = 144; }
            else              { w = wkvp + (o-720); ld = 432; }
            for (int c = 0; c < CS; ++c) {
                float wv = w[(size_t)c*ld];
                a0 += sS[0][c]*wv; a1 += sS[1][c]*wv;
                a2 += sS[2][c]*wv; a3 += sS[3][c]*wv;
            }
            float accs[4] = {a0,a1,a2,a3};
            if (o < 192) {
                float b = bq[o];
                for (int nn=0;nn<TN;++nn) q[(size_t)(n0+nn)*HC + o] = accs[nn] + b;
            } else if (o < 576) {
                int e = o-192; float b = bkv[e];
                int hh = e >> 5, sub = e & 31;
                for (int nn=0;nn<TN;++nn) {
                    float val = accs[nn] + b;
                    if (sub < CH) k[(size_t)(n0+nn)*HC + hh*CH + sub] = val;
                    else          v[(size_t)(n0+nn)*HC + hh*CH + (sub-CH)] = val;
                }
            } else if (o < 720) {
                int e = o-576; float b = bqp[e];
                for (int nn=0;nn<TN;++nn) sP[nn][e] = accs[nn] + b;
            } else {
                int e = o-720; float b = bkvp[e];
                for (int nn=0;nn<TN;++nn) sP[nn][144+e] = accs[nn] + b;
            }
        } else {
            int e = o - 1152;
            for (int c = 0; c < CZ; ++c) {
                float wv = wdz[(size_t)c*32 + e];
                a0 += sZ[0][c]*wv; a1 += sZ[1][c]*wv;
                a2 += sZ[2][c]*wv; a3 += sZ[3][c]*wv;
            }
            float accs[4]={a0,a1,a2,a3};
            float b = bdz[e];
            for (int nn=0;nn<TN;++nn) pz[(size_t)(n0+nn)*32 + e] = accs[nn] + b;
        }
    }
    __syncthreads();

    // rotate local points to global frame
    float* qp = ws + OFF_QP; float* kp = ws + OFF_KP; float* vp = ws + OFF_VP;
    for (int ptid = t; ptid < TN*192; ptid += 256) {
        int nn = ptid / 192, d = ptid % 192;
        int n = n0 + nn;
        float px, py, pzz;
        if (d < 48) { px = sP[nn][d];      py = sP[nn][48+d];      pzz = sP[nn][96+d]; }
        else { int dd=d-48; px = sP[nn][144+dd]; py = sP[nn][288+dd]; pzz = sP[nn][432+dd]; }
        const float* R = rot   + (size_t)n*9;
        const float* T = trans + (size_t)n*3;
        float gx = R[0]*px + R[1]*py + R[2]*pzz + T[0];
        float gy = R[3]*px + R[4]*py + R[5]*pzz + T[1];
        float gz = R[6]*px + R[7]*py + R[8]*pzz + T[2];
        if (d < 48) {                      // q_pts: d = h*4+p
            float* dst = qp + (size_t)n*144 + d*3;
            dst[0]=gx; dst[1]=gy; dst[2]=gz;
        } else {
            int dd = d-48; int hh = dd/12, pp = dd%12;   // kv_pts: d = h*12+p
            if (pp < PQ) { float* dst = kp + (size_t)n*144 + (hh*PQ+pp)*3;      dst[0]=gx; dst[1]=gy; dst[2]=gz; }
            else         { float* dst = vp + (size_t)n*288 + (hh*PV+(pp-PQ))*3; dst[0]=gx; dst[1]=gy; dst[2]=gz; }
        }
    }
}

// =====================================================================
// Kernel B: b_bcast[h][i][j] = (z[ridx[i],ridx[j],:] . w_b[:,h] + b_b[h]) * sqrt(1/3)
// block = one query row i, 256 threads x 2 j each. w_b in LDS (broadcast).
// =====================================================================
__global__ __launch_bounds__(256) void bpair_kernel(
    const float* __restrict__ z, const int* __restrict__ ridx,
    const float* __restrict__ wb, const float* __restrict__ bb,
    float* __restrict__ ws)
{
    __shared__ float4 sWb[CZ*3];          // [c][h/4], 128*3 float4
    const int t = threadIdx.x;
    const int i = blockIdx.x;
    for (int e = t; e < CZ*3; e += 256) sWb[e] = ((const float4*)wb)[e];
    __syncthreads();

    const int ri  = ridx[i];
    const int j0  = t, j1 = t + 256;
    const int rj0 = ridx[j0], rj1 = ridx[j1];
    const float4* zr0 = (const float4*)(z + ((size_t)ri*NRES + rj0)*CZ);
    const float4* zr1 = (const float4*)(z + ((size_t)ri*NRES + rj1)*CZ);

    float a0[12], a1[12];
    #pragma unroll
    for (int hh=0; hh<12; ++hh) { a0[hh]=0.f; a1[hh]=0.f; }

    #pragma unroll 4
    for (int c4 = 0; c4 < 32; ++c4) {
        float4 z0 = zr0[c4], z1 = zr1[c4];
        #pragma unroll
        for (int e = 0; e < 4; ++e) {
            const int c = (c4<<2) + e;
            float wv[12];
            *(float4*)&wv[0] = sWb[c*3+0];
            *(float4*)&wv[4] = sWb[c*3+1];
            *(float4*)&wv[8] = sWb[c*3+2];
            const float zv0 = (&z0.x)[e];
            const float zv1 = (&z1.x)[e];
            #pragma unroll
            for (int hh=0; hh<12; ++hh) { a0[hh] += zv0*wv[hh]; a1[hh] += zv1*wv[hh]; }
        }
    }
    const float SC = 0.57735026918962584f;   // sqrt(1/3)
    float* bbc = ws + OFF_B;
    #pragma unroll
    for (int hh = 0; hh < 12; ++hh) {
        float bias = bb[hh];
        bbc[((size_t)hh*NRIG + i)*NRIG + j0] = (a0[hh]+bias)*SC;
        bbc[((size_t)hh*NRIG + i)*NRIG + j1] = (a1[hh]+bias)*SC;
    }
}

// =====================================================================
// Kernel C: attention. block = (h, 4 queries), 256 threads.
// Full 512-logit row in regs/LDS, block softmax, 41-component output reduce.
// =====================================================================
__global__ __launch_bounds__(256) void attn_kernel(
    const float* __restrict__ hw_in, const float* __restrict__ mask,
    float* __restrict__ ws)
{
    constexpr int TI = 4;
    const int h    = blockIdx.x;
    const int i0   = blockIdx.y * TI;
    const int t    = threadIdx.x;
    const int lane = t & 63, wid = t >> 6;

    __shared__ float sQ[TI][16];
    __shared__ float sQP[TI][12];
    __shared__ float sE[TI][512];
    __shared__ float redM[TI][4], redS[TI][4];
    __shared__ float sMi[TI];

    const float* q  = ws + OFF_Q;  const float* k  = ws + OFF_K;  const float* v  = ws + OFF_V;
    const float* qp = ws + OFF_QP; const float* kp = ws + OFF_KP; const float* vp = ws + OFF_VP;
    const float* bbc = ws + OFF_B;

    for (int e = t; e < TI*16; e += 256) sQ[e/16][e%16]  = q[(size_t)(i0+e/16)*HC + h*CH + (e%16)];
    for (int e = t; e < TI*12; e += 256) sQP[e/12][e%12] = qp[(size_t)(i0+e/12)*144 + h*12 + (e%12)];
    if (t < TI) sMi[t] = mask[i0+t];
    __syncthreads();

    const float hwv = -0.5f * log1pf(__expf(hw_in[h])) * 0.13608276348795434f; // -0.5*softplus*sqrt(1/54)
    const float QKS = 0.14433756729740643f;                                    // sqrt(1/48)

    float lg[2][TI];
    float lmax[TI] = {-1e30f,-1e30f,-1e30f,-1e30f};
    #pragma unroll
    for (int jj = 0; jj < 2; ++jj) {
        int j = t + jj*256;
        float kk[16], kpv[12];
        const float4* kr = (const float4*)(k + (size_t)j*HC + h*CH);
        *(float4*)&kk[0]=kr[0]; *(float4*)&kk[4]=kr[1]; *(float4*)&kk[8]=kr[2]; *(float4*)&kk[12]=kr[3];
        const float4* kpr = (const float4*)(kp + (size_t)j*144 + h*12);
        *(float4*)&kpv[0]=kpr[0]; *(float4*)&kpv[4]=kpr[1]; *(float4*)&kpv[8]=kpr[2];
        float mj = mask[j];
        #pragma unroll
        for (int qq = 0; qq < TI; ++qq) {
            float dot = 0.f;
            #pragma unroll
            for (int c = 0; c < 16; ++c) dot += sQ[qq][c]*kk[c];
            float sq = 0.f;
            #pragma unroll
            for (int e = 0; e < 12; ++e) { float d = sQP[qq][e]-kpv[e]; sq += d*d; }
            float bv = bbc[((size_t)h*NRIG + (i0+qq))*NRIG + j];
            float lgt = dot*QKS + bv + hwv*sq + INF_*(sMi[qq]*mj - 1.0f);
            lg[jj][qq] = lgt;
            lmax[qq] = fmaxf(lmax[qq], lgt);
        }
    }
    // block max
    #pragma unroll
    for (int sft = 1; sft < 64; sft <<= 1)
        #pragma unroll
        for (int qq=0;qq<TI;++qq) lmax[qq] = fmaxf(lmax[qq], __shfl_xor(lmax[qq], sft));
    if (lane == 0) { for (int qq=0;qq<TI;++qq) redM[qq][wid] = lmax[qq]; }
    __syncthreads();
    float M[TI], psum[TI];
    #pragma unroll
    for (int qq=0;qq<TI;++qq) {
        M[qq] = fmaxf(fmaxf(redM[qq][0],redM[qq][1]),fmaxf(redM[qq][2],redM[qq][3]));
        psum[qq]=0.f;
    }
    #pragma unroll
    for (int jj = 0; jj < 2; ++jj) {
        int j = t + jj*256;
        #pragma unroll
        for (int qq=0;qq<TI;++qq) {
            float e = __expf(lg[jj][qq] - M[qq]);
            sE[qq][j] = e;
            psum[qq] += e;
        }
    }
    #pragma unroll
    for (int sft = 1; sft < 64; sft <<= 1)
        #pragma unroll
        for (int qq=0;qq<TI;++qq) psum[qq] += __shfl_xor(psum[qq], sft);
    if (lane == 0) { for (int qq=0;qq<TI;++qq) redS[qq][wid] = psum[qq]; }
    __syncthreads();
    float Sinv[TI];
    #pragma unroll
    for (int qq=0;qq<TI;++qq)
        Sinv[qq] = 1.0f/(redS[qq][0]+redS[qq][1]+redS[qq][2]+redS[qq][3]);

    // outputs: 16 (o) + 24 (o_pt_g) + 1 (rowsum) = 41 components
    float* o_ws = ws + OFF_O; float* optg = ws + OFF_OPT; float* rs = ws + OFF_RS;
    for (int comp = wid; comp < 41; comp += 4) {
        float part[TI] = {0.f,0.f,0.f,0.f};
        for (int jj = 0; jj < 8; ++jj) {
            int j = lane + jj*64;
            float val;
            if (comp < 16)      val = v [(size_t)j*HC  + h*CH + comp];
            else if (comp < 40) val = vp[(size_t)j*288 + h*24 + (comp-16)];
            else                val = 1.0f;
            #pragma unroll
            for (int qq=0;qq<TI;++qq) part[qq] += sE[qq][j]*val;
        }
        #pragma unroll
        for (int sft = 1; sft < 64; sft <<= 1)
            #pragma unroll
            for (int qq=0;qq<TI;++qq) part[qq] += __shfl_xor(part[qq], sft);
        if (lane == 0) {
            for (int qq=0;qq<TI;++qq) {
                float val = part[qq]*Sinv[qq];
                int n = i0+qq;
                if (comp < 16)      o_ws[((size_t)n*NH + h)*CH + comp] = val;
                else if (comp < 40) optg[((size_t)n*NH + h)*24 + (comp-16)] = val;
                else                rs[(size_t)n*NH + h] = val;
            }
        }
    }
}

// =====================================================================
// Kernel D: build feats (rotate-back, norm, o_pair) + feats @ w_out + b_out
// block = (col-chunk of 192, 4 rigids), 192 threads
// =====================================================================
__global__ __launch_bounds__(192) void out_kernel(
    const float* __restrict__ rot, const float* __restrict__ trans,
    const float* __restrict__ w_out, const float* __restrict__ b_out,
    const float* __restrict__ ws, float* __restrict__ out)
{
    constexpr int TI = 4;
    __shared__ float sF[TI][960];
    const int i0 = blockIdx.y*TI;
    const int c0 = blockIdx.x*192;
    const int t  = threadIdx.x;
    const float* o_ws = ws + OFF_O;  const float* optg = ws + OFF_OPT;
    const float* rs   = ws + OFF_RS; const float* pz   = ws + OFF_PZ;

    for (int e = t; e < TI*HC; e += 192)
        sF[e/HC][e%HC] = o_ws[(size_t)(i0 + e/HC)*HC + (e%HC)];
    for (int e = t; e < TI*96; e += 192) {
        int qq = e/96, hp = e%96; int n = i0+qq;
        const float* g = optg + ((size_t)n*NH + hp/PV)*24 + (hp%PV)*3;
        float gx = g[0]-trans[n*3+0], gy = g[1]-trans[n*3+1], gz = g[2]-trans[n*3+2];
        const float* R = rot + (size_t)n*9;
        float lx = R[0]*gx + R[3]*gy + R[6]*gz;   // rot^T
        float ly = R[1]*gx + R[4]*gy + R[7]*gz;
        float lz = R[2]*gx + R[5]*gy + R[8]*gz;
        sF[qq][192+hp] = lx; sF[qq][288+hp] = ly; sF[qq][384+hp] = lz;
        sF[qq][480+hp] = sqrtf(lx*lx+ly*ly+lz*lz + 1e-8f);
    }
    for (int e = t; e < TI*384; e += 192) {
        int qq = e/384, hd = e%384; int n = i0+qq;
        sF[qq][576+hd] = rs[(size_t)n*NH + hd/32] * pz[(size_t)n*32 + (hd%32)];
    }
    __syncthreads();

    const int col = c0 + t;
    float b = b_out[col];
    float a0=b, a1=b, a2=b, a3=b;
    for (int f = 0; f < 960; ++f) {
        float wv = w_out[(size_t)f*CS + col];
        a0 += sF[0][f]*wv; a1 += sF[1][f]*wv; a2 += sF[2][f]*wv; a3 += sF[3][f]*wv;
    }
    out[(size_t)(i0+0)*CS + col] = a0;
    out[(size_t)(i0+1)*CS + col] = a1;
    out[(size_t)(i0+2)*CS + col] = a2;
    out[(size_t)(i0+3)*CS + col] = a3;
}

// =====================================================================
extern "C" void kernel_launch(void* const* d_in, const int* in_sizes, int n_in,
                              void* d_out, int out_size, void* d_ws, size_t ws_size,
                              hipStream_t stream)
{
    const float* s     = (const float*)d_in[0];
    const float* z     = (const float*)d_in[1];
    const float* rot   = (const float*)d_in[2];
    const float* trans = (const float*)d_in[3];
    const float* mask  = (const float*)d_in[4];
    const int*   ridx  = (const int*)  d_in[5];
    const float* wq    = (const float*)d_in[6];
    const float* bq    = (const float*)d_in[7];
    const float* wkv   = (const float*)d_in[8];
    const float* bkv   = (const float*)d_in[9];
    const float* wqp   = (const float*)d_in[10];
    const float* bqp   = (const float*)d_in[11];
    const float* wkvp  = (const float*)d_in[12];
    const float* bkvp  = (const float*)d_in[13];
    const float* wb    = (const float*)d_in[14];
    const float* bb    = (const float*)d_in[15];
    const float* wdz   = (const float*)d_in[16];
    const float* bdz   = (const float*)d_in[17];
    const float* hw    = (const float*)d_in[18];
    const float* wout  = (const float*)d_in[19];
    const float* bout  = (const float*)d_in[20];
    float* ws  = (float*)d_ws;
    float* out = (float*)d_out;

    hipLaunchKernelGGL(proj_kernel, dim3(NRIG/4), dim3(256), 0, stream,
        s, z, rot, trans, ridx, wq,bq, wkv,bkv, wqp,bqp, wkvp,bkvp, wdz,bdz, ws);
    hipLaunchKernelGGL(bpair_kernel, dim3(NRIG), dim3(256), 0, stream,
        z, ridx, wb, bb, ws);
    hipLaunchKernelGGL(attn_kernel, dim3(NH, NRIG/4), dim3(256), 0, stream,
        hw, mask, ws);
    hipLaunchKernelGGL(out_kernel, dim3(2, NRIG/4), dim3(192), 0, stream,
        rot, trans, wout, bout, ws, out);
}

// Round 2
// 224.215 us; speedup vs baseline: 1.5333x; 1.5333x over previous
//
#include <hip/hip_runtime.h>
#include <hip/hip_bf16.h>
#include <math.h>

// ---------------- problem constants (B=1) ----------------
constexpr int NRIG = 512;
constexpr int NRES = 448;
constexpr int CS   = 384;
constexpr int CZ   = 128;
constexpr int CH   = 16;
constexpr int NH   = 12;
constexpr int PQ   = 4;
constexpr int PV   = 8;
constexpr int HC   = NH * CH;        // 192
constexpr float INF_ = 100000.0f;

// ---------------- workspace layout (floats) ----------------
constexpr size_t OFF_Q   = 0;                               // 512*192
constexpr size_t OFF_K   = OFF_Q   + (size_t)NRIG*HC;       // 512*192
constexpr size_t OFF_V   = OFF_K   + (size_t)NRIG*HC;       // 512*192
constexpr size_t OFF_QP  = OFF_V   + (size_t)NRIG*HC;       // 512*144
constexpr size_t OFF_KP  = OFF_QP  + (size_t)NRIG*NH*PQ*3;  // 512*144
constexpr size_t OFF_VP  = OFF_KP  + (size_t)NRIG*NH*PQ*3;  // 512*288
constexpr size_t OFF_PZ  = OFF_VP  + (size_t)NRIG*NH*PV*3;  // 512*32
constexpr size_t OFF_O   = OFF_PZ  + (size_t)NRIG*32;       // 512*192
constexpr size_t OFF_OPT = OFF_O   + (size_t)NRIG*HC;       // 512*288
constexpr size_t OFF_RS  = OFF_OPT + (size_t)NRIG*NH*PV*3;  // 512*12
constexpr size_t OFF_B   = OFF_RS  + (size_t)NRIG*NH;       // 12*512*512
// raw (un-rotated) point projections alias the b_bcast region: produced by
// proj_gemm, consumed by rotate_kernel, then overwritten by bpair_kernel.
constexpr size_t OFF_RAW = OFF_B;                            // 512*576

// =====================================================================
// Kernel A1: tiled GEMM  C[512][1152] = s[512][384] @ W[384][1152]
// W = concat(wq 192 | wkv 384 | wqp 144 | wkvp 432) by columns.
// BM=64 BN=32 BK=32, 256 threads, 4x2 micro-tile. grid = 8 x 36 = 288.
// q/k/v written directly; point cols written raw to OFF_RAW.
// =====================================================================
__global__ __launch_bounds__(256) void proj_gemm_kernel(
    const float* __restrict__ s,
    const float* __restrict__ wq,  const float* __restrict__ bq,
    const float* __restrict__ wkv, const float* __restrict__ bkv,
    const float* __restrict__ wqp, const float* __restrict__ bqp,
    const float* __restrict__ wkvp,const float* __restrict__ bkvp,
    float* __restrict__ ws)
{
    constexpr int BM=64, BN=32, BK=32, LDA=68;
    __shared__ float sA[BK][LDA];     // [kk][m], padded: conflict-free f4 reads
    __shared__ float sB[BK][BN];      // [kk][c]
    const int m0 = blockIdx.x * BM;
    const int c0 = blockIdx.y * BN;
    const int t  = threadIdx.x;
    const int tx = t & 15, ty = t >> 4;

    float acc[4][2] = {};

    for (int kt = 0; kt < CS/BK; ++kt) {
        const int k0 = kt*BK;
        // stage A: 512 quads, 2 per thread, coalesced along k
        #pragma unroll
        for (int r = 0; r < 2; ++r) {
            int qd = r*256 + t;
            int m = qd >> 3, kq = (qd & 7) << 2;
            float4 f = *(const float4*)(s + (size_t)(m0+m)*CS + k0 + kq);
            sA[kq+0][m] = f.x; sA[kq+1][m] = f.y;
            sA[kq+2][m] = f.z; sA[kq+3][m] = f.w;
        }
        // stage B: 256 quads, 1 per thread (boundaries 192/576/720 are %4==0)
        {
            int kk = t >> 3, c4 = (t & 7) << 2;
            int c = c0 + c4;
            const float* wp; int ld, co;
            if (c < 192)      { wp = wq;   ld = 192; co = c;     }
            else if (c < 576) { wp = wkv;  ld = 384; co = c-192; }
            else if (c < 720) { wp = wqp;  ld = 144; co = c-576; }
            else              { wp = wkvp; ld = 432; co = c-720; }
            float4 f = *(const float4*)(wp + (size_t)(k0+kk)*ld + co);
            *(float4*)&sB[kk][c4] = f;
        }
        __syncthreads();
        #pragma unroll
        for (int kk = 0; kk < BK; ++kk) {
            float4 a = *(const float4*)&sA[kk][ty*4];
            float2 b = *(const float2*)&sB[kk][tx*2];
            acc[0][0] += a.x*b.x; acc[0][1] += a.x*b.y;
            acc[1][0] += a.y*b.x; acc[1][1] += a.y*b.y;
            acc[2][0] += a.z*b.x; acc[2][1] += a.z*b.y;
            acc[3][0] += a.w*b.x; acc[3][1] += a.w*b.y;
        }
        __syncthreads();
    }

    float* q   = ws + OFF_Q;  float* k = ws + OFF_K;  float* v = ws + OFF_V;
    float* raw = ws + OFF_RAW;
    #pragma unroll
    for (int i = 0; i < 4; ++i)
        #pragma unroll
        for (int j = 0; j < 2; ++j) {
            int n = m0 + ty*4 + i;
            int c = c0 + tx*2 + j;
            if (c < 192) {
                q[(size_t)n*HC + c] = acc[i][j] + bq[c];
            } else if (c < 576) {
                int e = c-192; float val = acc[i][j] + bkv[e];
                int hh = e >> 5, sub = e & 31;
                if (sub < CH) k[(size_t)n*HC + hh*CH + sub] = val;
                else          v[(size_t)n*HC + hh*CH + (sub-CH)] = val;
            } else {
                int e = c-576;
                float bb_ = (c < 720) ? bqp[e] : bkvp[c-720];
                raw[(size_t)n*576 + e] = acc[i][j] + bb_;
            }
        }
}

// =====================================================================
// Kernel A2: rotate raw local-frame points to global frame -> qp/kp/vp
// one thread per (rigid, point). grid = 512*192/256 = 384.
// =====================================================================
__global__ __launch_bounds__(256) void rotate_kernel(
    const float* __restrict__ rot, const float* __restrict__ trans,
    float* __restrict__ ws)
{
    const int gid = blockIdx.x*256 + threadIdx.x;
    const int n = gid / 192, d = gid % 192;
    const float* raw = ws + OFF_RAW + (size_t)n*576;
    float px, py, pzz;
    if (d < 48) { px = raw[d];      py = raw[48+d];       pzz = raw[96+d]; }
    else { int dd = d-48; px = raw[144+dd]; py = raw[288+dd]; pzz = raw[432+dd]; }
    const float* R = rot   + (size_t)n*9;
    const float* T = trans + (size_t)n*3;
    float gx = R[0]*px + R[1]*py + R[2]*pzz + T[0];
    float gy = R[3]*px + R[4]*py + R[5]*pzz + T[1];
    float gz = R[6]*px + R[7]*py + R[8]*pzz + T[2];
    float* qp = ws + OFF_QP; float* kp = ws + OFF_KP; float* vp = ws + OFF_VP;
    if (d < 48) {                              // q_pts: d = h*4+p
        float* dst = qp + (size_t)n*144 + d*3;
        dst[0]=gx; dst[1]=gy; dst[2]=gz;
    } else {
        int dd = d-48; int hh = dd/12, pp = dd%12;  // kv_pts: d = h*12+p
        if (pp < PQ) { float* dst = kp + (size_t)n*144 + (hh*PQ+pp)*3;      dst[0]=gx; dst[1]=gy; dst[2]=gz; }
        else         { float* dst = vp + (size_t)n*288 + (hh*PV+(pp-PQ))*3; dst[0]=gx; dst[1]=gy; dst[2]=gz; }
    }
}

// =====================================================================
// Kernel B: b_bcast[h][i][j] = (z[ridx[i],ridx[j],:] . w_b[:,h] + b_b[h]) * sqrt(1/3)
// block = one query row i, 256 threads x 2 j each. w_b in LDS (broadcast).
// Also computes pz_diag[i] (32 outputs) on threads 0..31 at the end.
// =====================================================================
__global__ __launch_bounds__(256) void bpair_kernel(
    const float* __restrict__ z, const int* __restrict__ ridx,
    const float* __restrict__ wb, const float* __restrict__ bb,
    const float* __restrict__ wdz, const float* __restrict__ bdz,
    float* __restrict__ ws)
{
    __shared__ float4 sWb[CZ*3];          // [c][h/4], 128*3 float4
    __shared__ float sZd[CZ];             // z diag row for pz
    const int t = threadIdx.x;
    const int i = blockIdx.x;
    const int ri = ridx[i];
    for (int e = t; e < CZ*3; e += 256) sWb[e] = ((const float4*)wb)[e];
    if (t < CZ) sZd[t] = z[((size_t)ri*NRES + ri)*CZ + t];
    __syncthreads();

    const int j0  = t, j1 = t + 256;
    const int rj0 = ridx[j0], rj1 = ridx[j1];
    const float4* zr0 = (const float4*)(z + ((size_t)ri*NRES + rj0)*CZ);
    const float4* zr1 = (const float4*)(z + ((size_t)ri*NRES + rj1)*CZ);

    float a0[12], a1[12];
    #pragma unroll
    for (int hh=0; hh<12; ++hh) { a0[hh]=0.f; a1[hh]=0.f; }

    #pragma unroll 4
    for (int c4 = 0; c4 < 32; ++c4) {
        float4 z0 = zr0[c4], z1 = zr1[c4];
        #pragma unroll
        for (int e = 0; e < 4; ++e) {
            const int c = (c4<<2) + e;
            float wv[12];
            *(float4*)&wv[0] = sWb[c*3+0];
            *(float4*)&wv[4] = sWb[c*3+1];
            *(float4*)&wv[8] = sWb[c*3+2];
            const float zv0 = (&z0.x)[e];
            const float zv1 = (&z1.x)[e];
            #pragma unroll
            for (int hh=0; hh<12; ++hh) { a0[hh] += zv0*wv[hh]; a1[hh] += zv1*wv[hh]; }
        }
    }
    const float SC = 0.57735026918962584f;   // sqrt(1/3)
    float* bbc = ws + OFF_B;
    #pragma unroll
    for (int hh = 0; hh < 12; ++hh) {
        float bias = bb[hh];
        bbc[((size_t)hh*NRIG + i)*NRIG + j0] = (a0[hh]+bias)*SC;
        bbc[((size_t)hh*NRIG + i)*NRIG + j1] = (a1[hh]+bias)*SC;
    }
    // pz_diag for this rigid: 32 outputs, K=128
    if (t < 32) {
        float acc = 0.f;
        for (int c = 0; c < CZ; ++c) acc += sZd[c] * wdz[(size_t)c*32 + t];
        (ws + OFF_PZ)[(size_t)i*32 + t] = acc + bdz[t];
    }
}

// =====================================================================
// Kernel C: attention. block = (h, 4 queries), 256 threads.
// =====================================================================
__global__ __launch_bounds__(256) void attn_kernel(
    const float* __restrict__ hw_in, const float* __restrict__ mask,
    float* __restrict__ ws)
{
    constexpr int TI = 4;
    const int h    = blockIdx.x;
    const int i0   = blockIdx.y * TI;
    const int t    = threadIdx.x;
    const int lane = t & 63, wid = t >> 6;

    __shared__ float sQ[TI][16];
    __shared__ float sQP[TI][12];
    __shared__ float sE[TI][512];
    __shared__ float redM[TI][4], redS[TI][4];
    __shared__ float sMi[TI];

    const float* q  = ws + OFF_Q;  const float* k  = ws + OFF_K;  const float* v  = ws + OFF_V;
    const float* qp = ws + OFF_QP; const float* kp = ws + OFF_KP; const float* vp = ws + OFF_VP;
    const float* bbc = ws + OFF_B;

    for (int e = t; e < TI*16; e += 256) sQ[e/16][e%16]  = q[(size_t)(i0+e/16)*HC + h*CH + (e%16)];
    for (int e = t; e < TI*12; e += 256) sQP[e/12][e%12] = qp[(size_t)(i0+e/12)*144 + h*12 + (e%12)];
    if (t < TI) sMi[t] = mask[i0+t];
    __syncthreads();

    const float hwv = -0.5f * log1pf(__expf(hw_in[h])) * 0.13608276348795434f; // -0.5*softplus*sqrt(1/54)
    const float QKS = 0.14433756729740643f;                                    // sqrt(1/48)

    float lg[2][TI];
    float lmax[TI] = {-1e30f,-1e30f,-1e30f,-1e30f};
    #pragma unroll
    for (int jj = 0; jj < 2; ++jj) {
        int j = t + jj*256;
        float kk[16], kpv[12];
        const float4* kr = (const float4*)(k + (size_t)j*HC + h*CH);
        *(float4*)&kk[0]=kr[0]; *(float4*)&kk[4]=kr[1]; *(float4*)&kk[8]=kr[2]; *(float4*)&kk[12]=kr[3];
        const float4* kpr = (const float4*)(kp + (size_t)j*144 + h*12);
        *(float4*)&kpv[0]=kpr[0]; *(float4*)&kpv[4]=kpr[1]; *(float4*)&kpv[8]=kpr[2];
        float mj = mask[j];
        #pragma unroll
        for (int qq = 0; qq < TI; ++qq) {
            float dot = 0.f;
            #pragma unroll
            for (int c = 0; c < 16; ++c) dot += sQ[qq][c]*kk[c];
            float sq = 0.f;
            #pragma unroll
            for (int e = 0; e < 12; ++e) { float d = sQP[qq][e]-kpv[e]; sq += d*d; }
            float bv = bbc[((size_t)h*NRIG + (i0+qq))*NRIG + j];
            float lgt = dot*QKS + bv + hwv*sq + INF_*(sMi[qq]*mj - 1.0f);
            lg[jj][qq] = lgt;
            lmax[qq] = fmaxf(lmax[qq], lgt);
        }
    }
    #pragma unroll
    for (int sft = 1; sft < 64; sft <<= 1)
        #pragma unroll
        for (int qq=0;qq<TI;++qq) lmax[qq] = fmaxf(lmax[qq], __shfl_xor(lmax[qq], sft));
    if (lane == 0) { for (int qq=0;qq<TI;++qq) redM[qq][wid] = lmax[qq]; }
    __syncthreads();
    float M[TI], psum[TI];
    #pragma unroll
    for (int qq=0;qq<TI;++qq) {
        M[qq] = fmaxf(fmaxf(redM[qq][0],redM[qq][1]),fmaxf(redM[qq][2],redM[qq][3]));
        psum[qq]=0.f;
    }
    #pragma unroll
    for (int jj = 0; jj < 2; ++jj) {
        int j = t + jj*256;
        #pragma unroll
        for (int qq=0;qq<TI;++qq) {
            float e = __expf(lg[jj][qq] - M[qq]);
            sE[qq][j] = e;
            psum[qq] += e;
        }
    }
    #pragma unroll
    for (int sft = 1; sft < 64; sft <<= 1)
        #pragma unroll
        for (int qq=0;qq<TI;++qq) psum[qq] += __shfl_xor(psum[qq], sft);
    if (lane == 0) { for (int qq=0;qq<TI;++qq) redS[qq][wid] = psum[qq]; }
    __syncthreads();
    float Sinv[TI];
    #pragma unroll
    for (int qq=0;qq<TI;++qq)
        Sinv[qq] = 1.0f/(redS[qq][0]+redS[qq][1]+redS[qq][2]+redS[qq][3]);

    float* o_ws = ws + OFF_O; float* optg = ws + OFF_OPT; float* rs = ws + OFF_RS;
    for (int comp = wid; comp < 41; comp += 4) {
        float part[TI] = {0.f,0.f,0.f,0.f};
        for (int jj = 0; jj < 8; ++jj) {
            int j = lane + jj*64;
            float val;
            if (comp < 16)      val = v [(size_t)j*HC  + h*CH + comp];
            else if (comp < 40) val = vp[(size_t)j*288 + h*24 + (comp-16)];
            else                val = 1.0f;
            #pragma unroll
            for (int qq=0;qq<TI;++qq) part[qq] += sE[qq][j]*val;
        }
        #pragma unroll
        for (int sft = 1; sft < 64; sft <<= 1)
            #pragma unroll
            for (int qq=0;qq<TI;++qq) part[qq] += __shfl_xor(part[qq], sft);
        if (lane == 0) {
            for (int qq=0;qq<TI;++qq) {
                float val = part[qq]*Sinv[qq];
                int n = i0+qq;
                if (comp < 16)      o_ws[((size_t)n*NH + h)*CH + comp] = val;
                else if (comp < 40) optg[((size_t)n*NH + h)*24 + (comp-16)] = val;
                else                rs[(size_t)n*NH + h] = val;
            }
        }
    }
}

// =====================================================================
// Kernel D: build feats (rotate-back, norm, o_pair) + feats @ w_out + b_out
// =====================================================================
__global__ __launch_bounds__(192) void out_kernel(
    const float* __restrict__ rot, const float* __restrict__ trans,
    const float* __restrict__ w_out, const float* __restrict__ b_out,
    const float* __restrict__ ws, float* __restrict__ out)
{
    constexpr int TI = 4;
    __shared__ float sF[TI][960];
    const int i0 = blockIdx.y*TI;
    const int c0 = blockIdx.x*192;
    const int t  = threadIdx.x;
    const float* o_ws = ws + OFF_O;  const float* optg = ws + OFF_OPT;
    const float* rs   = ws + OFF_RS; const float* pz   = ws + OFF_PZ;

    for (int e = t; e < TI*HC; e += 192)
        sF[e/HC][e%HC] = o_ws[(size_t)(i0 + e/HC)*HC + (e%HC)];
    for (int e = t; e < TI*96; e += 192) {
        int qq = e/96, hp = e%96; int n = i0+qq;
        const float* g = optg + ((size_t)n*NH + hp/PV)*24 + (hp%PV)*3;
        float gx = g[0]-trans[n*3+0], gy = g[1]-trans[n*3+1], gz = g[2]-trans[n*3+2];
        const float* R = rot + (size_t)n*9;
        float lx = R[0]*gx + R[3]*gy + R[6]*gz;   // rot^T
        float ly = R[1]*gx + R[4]*gy + R[7]*gz;
        float lz = R[2]*gx + R[5]*gy + R[8]*gz;
        sF[qq][192+hp] = lx; sF[qq][288+hp] = ly; sF[qq][384+hp] = lz;
        sF[qq][480+hp] = sqrtf(lx*lx+ly*ly+lz*lz + 1e-8f);
    }
    for (int e = t; e < TI*384; e += 192) {
        int qq = e/384, hd = e%384; int n = i0+qq;
        sF[qq][576+hd] = rs[(size_t)n*NH + hd/32] * pz[(size_t)n*32 + (hd%32)];
    }
    __syncthreads();

    const int col = c0 + t;
    float b = b_out[col];
    float a0=b, a1=b, a2=b, a3=b;
    for (int f = 0; f < 960; ++f) {
        float wv = w_out[(size_t)f*CS + col];
        a0 += sF[0][f]*wv; a1 += sF[1][f]*wv; a2 += sF[2][f]*wv; a3 += sF[3][f]*wv;
    }
    out[(size_t)(i0+0)*CS + col] = a0;
    out[(size_t)(i0+1)*CS + col] = a1;
    out[(size_t)(i0+2)*CS + col] = a2;
    out[(size_t)(i0+3)*CS + col] = a3;
}

// =====================================================================
extern "C" void kernel_launch(void* const* d_in, const int* in_sizes, int n_in,
                              void* d_out, int out_size, void* d_ws, size_t ws_size,
                              hipStream_t stream)
{
    const float* s     = (const float*)d_in[0];
    const float* z     = (const float*)d_in[1];
    const float* rot   = (const float*)d_in[2];
    const float* trans = (const float*)d_in[3];
    const float* mask  = (const float*)d_in[4];
    const int*   ridx  = (const int*)  d_in[5];
    const float* wq    = (const float*)d_in[6];
    const float* bq    = (const float*)d_in[7];
    const float* wkv   = (const float*)d_in[8];
    const float* bkv   = (const float*)d_in[9];
    const float* wqp   = (const float*)d_in[10];
    const float* bqp   = (const float*)d_in[11];
    const float* wkvp  = (const float*)d_in[12];
    const float* bkvp  = (const float*)d_in[13];
    const float* wb    = (const float*)d_in[14];
    const float* bb    = (const float*)d_in[15];
    const float* wdz   = (const float*)d_in[16];
    const float* bdz   = (const float*)d_in[17];
    const float* hw    = (const float*)d_in[18];
    const float* wout  = (const float*)d_in[19];
    const float* bout  = (const float*)d_in[20];
    float* ws  = (float*)d_ws;
    float* out = (float*)d_out;

    hipLaunchKernelGGL(proj_gemm_kernel, dim3(NRIG/64, 1152/32), dim3(256), 0, stream,
        s, wq,bq, wkv,bkv, wqp,bqp, wkvp,bkvp, ws);
    hipLaunchKernelGGL(rotate_kernel, dim3(NRIG*192/256), dim3(256), 0, stream,
        rot, trans, ws);
    hipLaunchKernelGGL(bpair_kernel, dim3(NRIG), dim3(256), 0, stream,
        z, ridx, wb, bb, wdz, bdz, ws);
    hipLaunchKernelGGL(attn_kernel, dim3(NH, NRIG/4), dim3(256), 0, stream,
        hw, mask, ws);
    hipLaunchKernelGGL(out_kernel, dim3(2, NRIG/4), dim3(192), 0, stream,
        rot, trans, wout, bout, ws, out);
}

// Round 3
// 127.877 us; speedup vs baseline: 2.6884x; 1.7534x over previous
//
#include <hip/hip_runtime.h>
#include <hip/hip_bf16.h>
#include <math.h>

// ---------------- problem constants (B=1) ----------------
constexpr int NRIG = 512;
constexpr int NRES = 448;
constexpr int CS   = 384;
constexpr int CZ   = 128;
constexpr int CH   = 16;
constexpr int NH   = 12;
constexpr int PQ   = 4;
constexpr int PV   = 8;
constexpr int HC   = NH * CH;        // 192
constexpr float INF_ = 100000.0f;

// ---------------- workspace layout (floats), head-major ----------------
constexpr size_t OFF_Q   = 0;                                // [12][512][16]
constexpr size_t OFF_K   = OFF_Q   + (size_t)NH*NRIG*16;     // [12][512][16]
constexpr size_t OFF_QP  = OFF_K   + (size_t)NH*NRIG*16;     // [12][512][12]
constexpr size_t OFF_KP  = OFF_QP  + (size_t)NH*NRIG*12;     // [12][512][12]
constexpr size_t OFF_VT  = OFF_KP  + (size_t)NH*NRIG*12;     // [12][40][512]  (0..15 v, 16..39 vp)
constexpr size_t OFF_PZ  = OFF_VT  + (size_t)NH*40*NRIG;     // [512][32]
constexpr size_t OFF_O   = OFF_PZ  + (size_t)NRIG*32;        // [512][12][16]
constexpr size_t OFF_OPT = OFF_O   + (size_t)NRIG*HC;        // [512][12][24]
constexpr size_t OFF_RS  = OFF_OPT + (size_t)NRIG*NH*PV*3;   // [512][12]
constexpr size_t OFF_B   = OFF_RS  + (size_t)NRIG*NH;        // [12][512][512]
// raw (un-rotated) point projections alias the b_bcast region.
constexpr size_t OFF_RAW = OFF_B;                            // [512][576]

// =====================================================================
// Kernel A1: tiled GEMM  C[512][1152] = s[512][384] @ W[384][1152]
// =====================================================================
__global__ __launch_bounds__(256) void proj_gemm_kernel(
    const float* __restrict__ s,
    const float* __restrict__ wq,  const float* __restrict__ bq,
    const float* __restrict__ wkv, const float* __restrict__ bkv,
    const float* __restrict__ wqp, const float* __restrict__ bqp,
    const float* __restrict__ wkvp,const float* __restrict__ bkvp,
    float* __restrict__ ws)
{
    constexpr int BM=64, BN=32, BK=32, LDA=68;
    __shared__ float sA[BK][LDA];
    __shared__ float sB[BK][BN];
    const int m0 = blockIdx.x * BM;
    const int c0 = blockIdx.y * BN;
    const int t  = threadIdx.x;
    const int tx = t & 15, ty = t >> 4;

    float acc[4][2] = {};

    for (int kt = 0; kt < CS/BK; ++kt) {
        const int k0 = kt*BK;
        #pragma unroll
        for (int r = 0; r < 2; ++r) {
            int qd = r*256 + t;
            int m = qd >> 3, kq = (qd & 7) << 2;
            float4 f = *(const float4*)(s + (size_t)(m0+m)*CS + k0 + kq);
            sA[kq+0][m] = f.x; sA[kq+1][m] = f.y;
            sA[kq+2][m] = f.z; sA[kq+3][m] = f.w;
        }
        {
            int kk = t >> 3, c4 = (t & 7) << 2;
            int c = c0 + c4;
            const float* wp; int ld, co;
            if (c < 192)      { wp = wq;   ld = 192; co = c;     }
            else if (c < 576) { wp = wkv;  ld = 384; co = c-192; }
            else if (c < 720) { wp = wqp;  ld = 144; co = c-576; }
            else              { wp = wkvp; ld = 432; co = c-720; }
            float4 f = *(const float4*)(wp + (size_t)(k0+kk)*ld + co);
            *(float4*)&sB[kk][c4] = f;
        }
        __syncthreads();
        #pragma unroll
        for (int kk = 0; kk < BK; ++kk) {
            float4 a = *(const float4*)&sA[kk][ty*4];
            float2 b = *(const float2*)&sB[kk][tx*2];
            acc[0][0] += a.x*b.x; acc[0][1] += a.x*b.y;
            acc[1][0] += a.y*b.x; acc[1][1] += a.y*b.y;
            acc[2][0] += a.z*b.x; acc[2][1] += a.z*b.y;
            acc[3][0] += a.w*b.x; acc[3][1] += a.w*b.y;
        }
        __syncthreads();
    }

    float* qw  = ws + OFF_Q;  float* kw = ws + OFF_K;  float* vt = ws + OFF_VT;
    float* raw = ws + OFF_RAW;
    #pragma unroll
    for (int i = 0; i < 4; ++i)
        #pragma unroll
        for (int j = 0; j < 2; ++j) {
            int n = m0 + ty*4 + i;
            int c = c0 + tx*2 + j;
            if (c < 192) {
                int hh = c >> 4, cc = c & 15;
                qw[((size_t)hh*NRIG + n)*16 + cc] = acc[i][j] + bq[c];
            } else if (c < 576) {
                int e = c-192; float val = acc[i][j] + bkv[e];
                int hh = e >> 5, sub = e & 31;
                if (sub < CH) kw[((size_t)hh*NRIG + n)*16 + sub] = val;
                else          vt[((size_t)hh*40 + (sub-CH))*NRIG + n] = val;
            } else {
                int e = c-576;
                float bb_ = (c < 720) ? bqp[e] : bkvp[c-720];
                raw[(size_t)n*576 + e] = acc[i][j] + bb_;
            }
        }
}

// =====================================================================
// Kernel A2: rotate raw local points -> global frame (head-major outputs)
// =====================================================================
__global__ __launch_bounds__(256) void rotate_kernel(
    const float* __restrict__ rot, const float* __restrict__ trans,
    float* __restrict__ ws)
{
    const int gid = blockIdx.x*256 + threadIdx.x;
    const int n = gid / 192, d = gid % 192;
    const float* raw = ws + OFF_RAW + (size_t)n*576;
    float px, py, pzz;
    if (d < 48) { px = raw[d];      py = raw[48+d];       pzz = raw[96+d]; }
    else { int dd = d-48; px = raw[144+dd]; py = raw[288+dd]; pzz = raw[432+dd]; }
    const float* R = rot   + (size_t)n*9;
    const float* T = trans + (size_t)n*3;
    float gx = R[0]*px + R[1]*py + R[2]*pzz + T[0];
    float gy = R[3]*px + R[4]*py + R[5]*pzz + T[1];
    float gz = R[6]*px + R[7]*py + R[8]*pzz + T[2];
    if (d < 48) {                              // q_pts: d = h*4+p
        int hh = d >> 2, pp = d & 3;
        float* dst = ws + OFF_QP + ((size_t)hh*NRIG + n)*12 + pp*3;
        dst[0]=gx; dst[1]=gy; dst[2]=gz;
    } else {
        int dd = d-48; int hh = dd/12, pp = dd%12;  // kv_pts
        if (pp < PQ) {
            float* dst = ws + OFF_KP + ((size_t)hh*NRIG + n)*12 + pp*3;
            dst[0]=gx; dst[1]=gy; dst[2]=gz;
        } else {
            float* vt = ws + OFF_VT + ((size_t)hh*40 + 16 + (pp-PQ)*3)*NRIG + n;
            vt[0*NRIG]=gx; vt[1*NRIG]=gy; vt[2*NRIG]=gz;
        }
    }
}

// =====================================================================
// Kernel B: b_bcast + pz_diag (unchanged)
// =====================================================================
__global__ __launch_bounds__(256) void bpair_kernel(
    const float* __restrict__ z, const int* __restrict__ ridx,
    const float* __restrict__ wb, const float* __restrict__ bb,
    const float* __restrict__ wdz, const float* __restrict__ bdz,
    float* __restrict__ ws)
{
    __shared__ float4 sWb[CZ*3];
    __shared__ float sZd[CZ];
    const int t = threadIdx.x;
    const int i = blockIdx.x;
    const int ri = ridx[i];
    for (int e = t; e < CZ*3; e += 256) sWb[e] = ((const float4*)wb)[e];
    if (t < CZ) sZd[t] = z[((size_t)ri*NRES + ri)*CZ + t];
    __syncthreads();

    const int j0  = t, j1 = t + 256;
    const int rj0 = ridx[j0], rj1 = ridx[j1];
    const float4* zr0 = (const float4*)(z + ((size_t)ri*NRES + rj0)*CZ);
    const float4* zr1 = (const float4*)(z + ((size_t)ri*NRES + rj1)*CZ);

    float a0[12], a1[12];
    #pragma unroll
    for (int hh=0; hh<12; ++hh) { a0[hh]=0.f; a1[hh]=0.f; }

    #pragma unroll 4
    for (int c4 = 0; c4 < 32; ++c4) {
        float4 z0 = zr0[c4], z1 = zr1[c4];
        #pragma unroll
        for (int e = 0; e < 4; ++e) {
            const int c = (c4<<2) + e;
            float wv[12];
            *(float4*)&wv[0] = sWb[c*3+0];
            *(float4*)&wv[4] = sWb[c*3+1];
            *(float4*)&wv[8] = sWb[c*3+2];
            const float zv0 = (&z0.x)[e];
            const float zv1 = (&z1.x)[e];
            #pragma unroll
            for (int hh=0; hh<12; ++hh) { a0[hh] += zv0*wv[hh]; a1[hh] += zv1*wv[hh]; }
        }
    }
    const float SC = 0.57735026918962584f;
    float* bbc = ws + OFF_B;
    #pragma unroll
    for (int hh = 0; hh < 12; ++hh) {
        float bias = bb[hh];
        bbc[((size_t)hh*NRIG + i)*NRIG + j0] = (a0[hh]+bias)*SC;
        bbc[((size_t)hh*NRIG + i)*NRIG + j1] = (a1[hh]+bias)*SC;
    }
    if (t < 32) {
        float acc = 0.f;
        for (int c = 0; c < CZ; ++c) acc += sZd[c] * wdz[(size_t)c*32 + t];
        (ws + OFF_PZ)[(size_t)i*32 + t] = acc + bdz[t];
    }
}

// =====================================================================
// Kernel C: attention. block = (h, 4 queries), 256 threads.
// Phase 1: logits (head-major K/KP). Phase 2: comp-split output GEMM
// against transposed VT (coalesced), 2 shuffle rounds + LDS tree.
// =====================================================================
__global__ __launch_bounds__(256) void attn_kernel(
    const float* __restrict__ hw_in, const float* __restrict__ mask,
    float* __restrict__ ws)
{
    constexpr int TI = 4;
    const int h    = blockIdx.x;
    const int i0   = blockIdx.y * TI;
    const int t    = threadIdx.x;
    const int lane = t & 63, wid = t >> 6;

    __shared__ float sQ[TI][16];
    __shared__ float sQP[TI][12];
    __shared__ float sE[TI][512];
    __shared__ float redM[TI][4], redS[TI][4];
    __shared__ float sMi[TI];
    __shared__ float sP[TI][16][44];   // partial sums: [qq][lane-group][comp]

    const float* qw  = ws + OFF_Q  + (size_t)h*NRIG*16;
    const float* kw  = ws + OFF_K  + (size_t)h*NRIG*16;
    const float* qpw = ws + OFF_QP + (size_t)h*NRIG*12;
    const float* kpw = ws + OFF_KP + (size_t)h*NRIG*12;
    const float* vt  = ws + OFF_VT + (size_t)h*40*NRIG;
    const float* bbc = ws + OFF_B  + (size_t)h*NRIG*NRIG;

    for (int e = t; e < TI*16; e += 256) sQ[e/16][e%16]  = qw[(size_t)(i0+e/16)*16 + (e%16)];
    for (int e = t; e < TI*12; e += 256) sQP[e/12][e%12] = qpw[(size_t)(i0+e/12)*12 + (e%12)];
    if (t < TI) sMi[t] = mask[i0+t];
    __syncthreads();

    const float hwv = -0.5f * log1pf(__expf(hw_in[h])) * 0.13608276348795434f;
    const float QKS = 0.14433756729740643f;

    float lg[2][TI];
    float lmax[TI] = {-1e30f,-1e30f,-1e30f,-1e30f};
    #pragma unroll
    for (int jj = 0; jj < 2; ++jj) {
        int j = t + jj*256;
        float kk[16], kpv[12];
        const float4* kr = (const float4*)(kw + (size_t)j*16);
        *(float4*)&kk[0]=kr[0]; *(float4*)&kk[4]=kr[1]; *(float4*)&kk[8]=kr[2]; *(float4*)&kk[12]=kr[3];
        const float4* kpr = (const float4*)(kpw + (size_t)j*12);
        *(float4*)&kpv[0]=kpr[0]; *(float4*)&kpv[4]=kpr[1]; *(float4*)&kpv[8]=kpr[2];
        float mj = mask[j];
        #pragma unroll
        for (int qq = 0; qq < TI; ++qq) {
            float dot = 0.f;
            #pragma unroll
            for (int c = 0; c < 16; ++c) dot += sQ[qq][c]*kk[c];
            float sq = 0.f;
            #pragma unroll
            for (int e = 0; e < 12; ++e) { float d = sQP[qq][e]-kpv[e]; sq += d*d; }
            float bv = bbc[(size_t)(i0+qq)*NRIG + j];
            float lgt = dot*QKS + bv + hwv*sq + INF_*(sMi[qq]*mj - 1.0f);
            lg[jj][qq] = lgt;
            lmax[qq] = fmaxf(lmax[qq], lgt);
        }
    }
    #pragma unroll
    for (int sft = 1; sft < 64; sft <<= 1)
        #pragma unroll
        for (int qq=0;qq<TI;++qq) lmax[qq] = fmaxf(lmax[qq], __shfl_xor(lmax[qq], sft));
    if (lane == 0) { for (int qq=0;qq<TI;++qq) redM[qq][wid] = lmax[qq]; }
    __syncthreads();
    float M[TI], psum[TI];
    #pragma unroll
    for (int qq=0;qq<TI;++qq) {
        M[qq] = fmaxf(fmaxf(redM[qq][0],redM[qq][1]),fmaxf(redM[qq][2],redM[qq][3]));
        psum[qq]=0.f;
    }
    #pragma unroll
    for (int jj = 0; jj < 2; ++jj) {
        int j = t + jj*256;
        #pragma unroll
        for (int qq=0;qq<TI;++qq) {
            float e = __expf(lg[jj][qq] - M[qq]);
            sE[qq][j] = e;
            psum[qq] += e;
        }
    }
    #pragma unroll
    for (int sft = 1; sft < 64; sft <<= 1)
        #pragma unroll
        for (int qq=0;qq<TI;++qq) psum[qq] += __shfl_xor(psum[qq], sft);
    if (lane == 0) { for (int qq=0;qq<TI;++qq) redS[qq][wid] = psum[qq]; }
    __syncthreads();

    // ---------- phase 2: output GEMM, wave wid owns comps wid*10..+9 ----------
    {
        const int c0 = wid*10;
        float acc[10][TI];
        #pragma unroll
        for (int ci=0;ci<10;++ci)
            #pragma unroll
            for (int qq=0;qq<TI;++qq) acc[ci][qq]=0.f;

        #pragma unroll
        for (int m = 0; m < 8; ++m) {
            const int j = lane + 64*m;
            float ev[TI];
            #pragma unroll
            for (int qq=0;qq<TI;++qq) ev[qq] = sE[qq][j];     // conflict-free LDS
            #pragma unroll
            for (int ci = 0; ci < 10; ++ci) {
                float vv = vt[(size_t)(c0+ci)*NRIG + j];       // coalesced global
                #pragma unroll
                for (int qq=0;qq<TI;++qq) acc[ci][qq] += ev[qq]*vv;
            }
        }
        // 2 shuffle rounds: 64 -> 16 partials
        #pragma unroll
        for (int ci=0;ci<10;++ci)
            #pragma unroll
            for (int qq=0;qq<TI;++qq) {
                acc[ci][qq] += __shfl_xor(acc[ci][qq], 1);
                acc[ci][qq] += __shfl_xor(acc[ci][qq], 2);
            }
        if ((lane & 3) == 0) {
            const int g = lane >> 2;
            #pragma unroll
            for (int qq=0;qq<TI;++qq)
                #pragma unroll
                for (int ci=0;ci<10;++ci)
                    sP[qq][g][c0+ci] = acc[ci][qq];
        }
    }
    __syncthreads();

    // ---------- epilogue: 164 outputs ----------
    if (t < TI*41) {
        const int qq = t / 41, c = t % 41;
        const int n = i0 + qq;
        float S = redS[qq][0]+redS[qq][1]+redS[qq][2]+redS[qq][3];
        float Sinv = 1.0f / S;
        if (c == 40) {
            (ws + OFF_RS)[(size_t)n*NH + h] = S * Sinv;
        } else {
            float acc = 0.f;
            #pragma unroll
            for (int g = 0; g < 16; ++g) acc += sP[qq][g][c];
            acc *= Sinv;
            if (c < 16) (ws + OFF_O  )[((size_t)n*NH + h)*CH + c]      = acc;
            else        (ws + OFF_OPT)[((size_t)n*NH + h)*24 + (c-16)] = acc;
        }
    }
}

// =====================================================================
// Kernel D: build feats + feats @ w_out + b_out (unchanged)
// =====================================================================
__global__ __launch_bounds__(192) void out_kernel(
    const float* __restrict__ rot, const float* __restrict__ trans,
    const float* __restrict__ w_out, const float* __restrict__ b_out,
    const float* __restrict__ ws, float* __restrict__ out)
{
    constexpr int TI = 4;
    __shared__ float sF[TI][960];
    const int i0 = blockIdx.y*TI;
    const int c0 = blockIdx.x*192;
    const int t  = threadIdx.x;
    const float* o_ws = ws + OFF_O;  const float* optg = ws + OFF_OPT;
    const float* rs   = ws + OFF_RS; const float* pz   = ws + OFF_PZ;

    for (int e = t; e < TI*HC; e += 192)
        sF[e/HC][e%HC] = o_ws[(size_t)(i0 + e/HC)*HC + (e%HC)];
    for (int e = t; e < TI*96; e += 192) {
        int qq = e/96, hp = e%96; int n = i0+qq;
        const float* g = optg + ((size_t)n*NH + hp/PV)*24 + (hp%PV)*3;
        float gx = g[0]-trans[n*3+0], gy = g[1]-trans[n*3+1], gz = g[2]-trans[n*3+2];
        const float* R = rot + (size_t)n*9;
        float lx = R[0]*gx + R[3]*gy + R[6]*gz;
        float ly = R[1]*gx + R[4]*gy + R[7]*gz;
        float lz = R[2]*gx + R[5]*gy + R[8]*gz;
        sF[qq][192+hp] = lx; sF[qq][288+hp] = ly; sF[qq][384+hp] = lz;
        sF[qq][480+hp] = sqrtf(lx*lx+ly*ly+lz*lz + 1e-8f);
    }
    for (int e = t; e < TI*384; e += 192) {
        int qq = e/384, hd = e%384; int n = i0+qq;
        sF[qq][576+hd] = rs[(size_t)n*NH + hd/32] * pz[(size_t)n*32 + (hd%32)];
    }
    __syncthreads();

    const int col = c0 + t;
    float b = b_out[col];
    float a0=b, a1=b, a2=b, a3=b;
    for (int f = 0; f < 960; ++f) {
        float wv = w_out[(size_t)f*CS + col];
        a0 += sF[0][f]*wv; a1 += sF[1][f]*wv; a2 += sF[2][f]*wv; a3 += sF[3][f]*wv;
    }
    out[(size_t)(i0+0)*CS + col] = a0;
    out[(size_t)(i0+1)*CS + col] = a1;
    out[(size_t)(i0+2)*CS + col] = a2;
    out[(size_t)(i0+3)*CS + col] = a3;
}

// =====================================================================
extern "C" void kernel_launch(void* const* d_in, const int* in_sizes, int n_in,
                              void* d_out, int out_size, void* d_ws, size_t ws_size,
                              hipStream_t stream)
{
    const float* s     = (const float*)d_in[0];
    const float* z     = (const float*)d_in[1];
    const float* rot   = (const float*)d_in[2];
    const float* trans = (const float*)d_in[3];
    const float* mask  = (const float*)d_in[4];
    const int*   ridx  = (const int*)  d_in[5];
    const float* wq    = (const float*)d_in[6];
    const float* bq    = (const float*)d_in[7];
    const float* wkv   = (const float*)d_in[8];
    const float* bkv   = (const float*)d_in[9];
    const float* wqp   = (const float*)d_in[10];
    const float* bqp   = (const float*)d_in[11];
    const float* wkvp  = (const float*)d_in[12];
    const float* bkvp  = (const float*)d_in[13];
    const float* wb    = (const float*)d_in[14];
    const float* bb    = (const float*)d_in[15];
    const float* wdz   = (const float*)d_in[16];
    const float* bdz   = (const float*)d_in[17];
    const float* hw    = (const float*)d_in[18];
    const float* wout  = (const float*)d_in[19];
    const float* bout  = (const float*)d_in[20];
    float* ws  = (float*)d_ws;
    float* out = (float*)d_out;

    hipLaunchKernelGGL(proj_gemm_kernel, dim3(NRIG/64, 1152/32), dim3(256), 0, stream,
        s, wq,bq, wkv,bkv, wqp,bqp, wkvp,bkvp, ws);
    hipLaunchKernelGGL(rotate_kernel, dim3(NRIG*192/256), dim3(256), 0, stream,
        rot, trans, ws);
    hipLaunchKernelGGL(bpair_kernel, dim3(NRIG), dim3(256), 0, stream,
        z, ridx, wb, bb, wdz, bdz, ws);
    hipLaunchKernelGGL(attn_kernel, dim3(NH, NRIG/4), dim3(256), 0, stream,
        hw, mask, ws);
    hipLaunchKernelGGL(out_kernel, dim3(2, NRIG/4), dim3(192), 0, stream,
        rot, trans, wout, bout, ws, out);
}

// Round 4
// 122.024 us; speedup vs baseline: 2.8174x; 1.0480x over previous
//
#include <hip/hip_runtime.h>
#include <hip/hip_bf16.h>
#include <math.h>

// ---------------- problem constants (B=1) ----------------
constexpr int NRIG = 512;
constexpr int NRES = 448;
constexpr int CS   = 384;
constexpr int CZ   = 128;
constexpr int CH   = 16;
constexpr int NH   = 12;
constexpr int PQ   = 4;
constexpr int PV   = 8;
constexpr int HC   = NH * CH;        // 192
constexpr float INF_ = 100000.0f;

// ---------------- workspace layout (floats), head-major ----------------
constexpr size_t OFF_Q   = 0;                                // [12][512][16]
constexpr size_t OFF_K   = OFF_Q   + (size_t)NH*NRIG*16;     // [12][512][16]
constexpr size_t OFF_QP  = OFF_K   + (size_t)NH*NRIG*16;     // [12][512][12]
constexpr size_t OFF_KP  = OFF_QP  + (size_t)NH*NRIG*12;     // [12][512][12]
constexpr size_t OFF_VT  = OFF_KP  + (size_t)NH*NRIG*12;     // [12][40][512]  (0..15 v, 16..39 vp)
constexpr size_t OFF_PZ  = OFF_VT  + (size_t)NH*40*NRIG;     // [512][32]
constexpr size_t OFF_O   = OFF_PZ  + (size_t)NRIG*32;        // [512][12][16]
constexpr size_t OFF_OPT = OFF_O   + (size_t)NRIG*HC;        // [512][12][24]
constexpr size_t OFF_RS  = OFF_OPT + (size_t)NRIG*NH*PV*3;   // [512][12]
constexpr size_t OFF_B   = OFF_RS  + (size_t)NRIG*NH;        // [12][512][512]
// Aliases of the b_bcast region (stream-ordered: raw -> bbc -> feats):
constexpr size_t OFF_RAW = OFF_B;                            // [512][576]
constexpr size_t OFF_F   = OFF_B;                            // [512][960] feats

// =====================================================================
// Kernel A1: tiled GEMM  C[512][1152] = s[512][384] @ W[384][1152]
// =====================================================================
__global__ __launch_bounds__(256) void proj_gemm_kernel(
    const float* __restrict__ s,
    const float* __restrict__ wq,  const float* __restrict__ bq,
    const float* __restrict__ wkv, const float* __restrict__ bkv,
    const float* __restrict__ wqp, const float* __restrict__ bqp,
    const float* __restrict__ wkvp,const float* __restrict__ bkvp,
    float* __restrict__ ws)
{
    constexpr int BM=64, BN=32, BK=32, LDA=68;
    __shared__ float sA[BK][LDA];
    __shared__ float sB[BK][BN];
    const int m0 = blockIdx.x * BM;
    const int c0 = blockIdx.y * BN;
    const int t  = threadIdx.x;
    const int tx = t & 15, ty = t >> 4;

    float acc[4][2] = {};

    for (int kt = 0; kt < CS/BK; ++kt) {
        const int k0 = kt*BK;
        #pragma unroll
        for (int r = 0; r < 2; ++r) {
            int qd = r*256 + t;
            int m = qd >> 3, kq = (qd & 7) << 2;
            float4 f = *(const float4*)(s + (size_t)(m0+m)*CS + k0 + kq);
            sA[kq+0][m] = f.x; sA[kq+1][m] = f.y;
            sA[kq+2][m] = f.z; sA[kq+3][m] = f.w;
        }
        {
            int kk = t >> 3, c4 = (t & 7) << 2;
            int c = c0 + c4;
            const float* wp; int ld, co;
            if (c < 192)      { wp = wq;   ld = 192; co = c;     }
            else if (c < 576) { wp = wkv;  ld = 384; co = c-192; }
            else if (c < 720) { wp = wqp;  ld = 144; co = c-576; }
            else              { wp = wkvp; ld = 432; co = c-720; }
            float4 f = *(const float4*)(wp + (size_t)(k0+kk)*ld + co);
            *(float4*)&sB[kk][c4] = f;
        }
        __syncthreads();
        #pragma unroll
        for (int kk = 0; kk < BK; ++kk) {
            float4 a = *(const float4*)&sA[kk][ty*4];
            float2 b = *(const float2*)&sB[kk][tx*2];
            acc[0][0] += a.x*b.x; acc[0][1] += a.x*b.y;
            acc[1][0] += a.y*b.x; acc[1][1] += a.y*b.y;
            acc[2][0] += a.z*b.x; acc[2][1] += a.z*b.y;
            acc[3][0] += a.w*b.x; acc[3][1] += a.w*b.y;
        }
        __syncthreads();
    }

    float* qw  = ws + OFF_Q;  float* kw = ws + OFF_K;  float* vt = ws + OFF_VT;
    float* raw = ws + OFF_RAW;
    #pragma unroll
    for (int i = 0; i < 4; ++i)
        #pragma unroll
        for (int j = 0; j < 2; ++j) {
            int n = m0 + ty*4 + i;
            int c = c0 + tx*2 + j;
            if (c < 192) {
                int hh = c >> 4, cc = c & 15;
                qw[((size_t)hh*NRIG + n)*16 + cc] = acc[i][j] + bq[c];
            } else if (c < 576) {
                int e = c-192; float val = acc[i][j] + bkv[e];
                int hh = e >> 5, sub = e & 31;
                if (sub < CH) kw[((size_t)hh*NRIG + n)*16 + sub] = val;
                else          vt[((size_t)hh*40 + (sub-CH))*NRIG + n] = val;
            } else {
                int e = c-576;
                float bb_ = (c < 720) ? bqp[e] : bkvp[c-720];
                raw[(size_t)n*576 + e] = acc[i][j] + bb_;
            }
        }
}

// =====================================================================
// Kernel A2: rotate raw local points -> global frame (head-major outputs)
// =====================================================================
__global__ __launch_bounds__(256) void rotate_kernel(
    const float* __restrict__ rot, const float* __restrict__ trans,
    float* __restrict__ ws)
{
    const int gid = blockIdx.x*256 + threadIdx.x;
    const int n = gid / 192, d = gid % 192;
    const float* raw = ws + OFF_RAW + (size_t)n*576;
    float px, py, pzz;
    if (d < 48) { px = raw[d];      py = raw[48+d];       pzz = raw[96+d]; }
    else { int dd = d-48; px = raw[144+dd]; py = raw[288+dd]; pzz = raw[432+dd]; }
    const float* R = rot   + (size_t)n*9;
    const float* T = trans + (size_t)n*3;
    float gx = R[0]*px + R[1]*py + R[2]*pzz + T[0];
    float gy = R[3]*px + R[4]*py + R[5]*pzz + T[1];
    float gz = R[6]*px + R[7]*py + R[8]*pzz + T[2];
    if (d < 48) {                              // q_pts: d = h*4+p
        int hh = d >> 2, pp = d & 3;
        float* dst = ws + OFF_QP + ((size_t)hh*NRIG + n)*12 + pp*3;
        dst[0]=gx; dst[1]=gy; dst[2]=gz;
    } else {
        int dd = d-48; int hh = dd/12, pp = dd%12;  // kv_pts
        if (pp < PQ) {
            float* dst = ws + OFF_KP + ((size_t)hh*NRIG + n)*12 + pp*3;
            dst[0]=gx; dst[1]=gy; dst[2]=gz;
        } else {
            float* vt = ws + OFF_VT + ((size_t)hh*40 + 16 + (pp-PQ)*3)*NRIG + n;
            vt[0*NRIG]=gx; vt[1*NRIG]=gy; vt[2*NRIG]=gz;
        }
    }
}

// =====================================================================
// Kernel B: b_bcast + pz_diag
// =====================================================================
__global__ __launch_bounds__(256) void bpair_kernel(
    const float* __restrict__ z, const int* __restrict__ ridx,
    const float* __restrict__ wb, const float* __restrict__ bb,
    const float* __restrict__ wdz, const float* __restrict__ bdz,
    float* __restrict__ ws)
{
    __shared__ float4 sWb[CZ*3];
    __shared__ float sZd[CZ];
    const int t = threadIdx.x;
    const int i = blockIdx.x;
    const int ri = ridx[i];
    for (int e = t; e < CZ*3; e += 256) sWb[e] = ((const float4*)wb)[e];
    if (t < CZ) sZd[t] = z[((size_t)ri*NRES + ri)*CZ + t];
    __syncthreads();

    const int j0  = t, j1 = t + 256;
    const int rj0 = ridx[j0], rj1 = ridx[j1];
    const float4* zr0 = (const float4*)(z + ((size_t)ri*NRES + rj0)*CZ);
    const float4* zr1 = (const float4*)(z + ((size_t)ri*NRES + rj1)*CZ);

    float a0[12], a1[12];
    #pragma unroll
    for (int hh=0; hh<12; ++hh) { a0[hh]=0.f; a1[hh]=0.f; }

    #pragma unroll 4
    for (int c4 = 0; c4 < 32; ++c4) {
        float4 z0 = zr0[c4], z1 = zr1[c4];
        #pragma unroll
        for (int e = 0; e < 4; ++e) {
            const int c = (c4<<2) + e;
            float wv[12];
            *(float4*)&wv[0] = sWb[c*3+0];
            *(float4*)&wv[4] = sWb[c*3+1];
            *(float4*)&wv[8] = sWb[c*3+2];
            const float zv0 = (&z0.x)[e];
            const float zv1 = (&z1.x)[e];
            #pragma unroll
            for (int hh=0; hh<12; ++hh) { a0[hh] += zv0*wv[hh]; a1[hh] += zv1*wv[hh]; }
        }
    }
    const float SC = 0.57735026918962584f;
    float* bbc = ws + OFF_B;
    #pragma unroll
    for (int hh = 0; hh < 12; ++hh) {
        float bias = bb[hh];
        bbc[((size_t)hh*NRIG + i)*NRIG + j0] = (a0[hh]+bias)*SC;
        bbc[((size_t)hh*NRIG + i)*NRIG + j1] = (a1[hh]+bias)*SC;
    }
    if (t < 32) {
        float acc = 0.f;
        for (int c = 0; c < CZ; ++c) acc += sZd[c] * wdz[(size_t)c*32 + t];
        (ws + OFF_PZ)[(size_t)i*32 + t] = acc + bdz[t];
    }
}

// =====================================================================
// Kernel C: attention. block = (h, 4 queries), 256 threads.
// =====================================================================
__global__ __launch_bounds__(256) void attn_kernel(
    const float* __restrict__ hw_in, const float* __restrict__ mask,
    float* __restrict__ ws)
{
    constexpr int TI = 4;
    const int h    = blockIdx.x;
    const int i0   = blockIdx.y * TI;
    const int t    = threadIdx.x;
    const int lane = t & 63, wid = t >> 6;

    __shared__ float sQ[TI][16];
    __shared__ float sQP[TI][12];
    __shared__ float sE[TI][512];
    __shared__ float redM[TI][4], redS[TI][4];
    __shared__ float sMi[TI];
    __shared__ float sP[TI][16][44];

    const float* qw  = ws + OFF_Q  + (size_t)h*NRIG*16;
    const float* kw  = ws + OFF_K  + (size_t)h*NRIG*16;
    const float* qpw = ws + OFF_QP + (size_t)h*NRIG*12;
    const float* kpw = ws + OFF_KP + (size_t)h*NRIG*12;
    const float* vt  = ws + OFF_VT + (size_t)h*40*NRIG;
    const float* bbc = ws + OFF_B  + (size_t)h*NRIG*NRIG;

    for (int e = t; e < TI*16; e += 256) sQ[e/16][e%16]  = qw[(size_t)(i0+e/16)*16 + (e%16)];
    for (int e = t; e < TI*12; e += 256) sQP[e/12][e%12] = qpw[(size_t)(i0+e/12)*12 + (e%12)];
    if (t < TI) sMi[t] = mask[i0+t];
    __syncthreads();

    const float hwv = -0.5f * log1pf(__expf(hw_in[h])) * 0.13608276348795434f;
    const float QKS = 0.14433756729740643f;

    float lg[2][TI];
    float lmax[TI] = {-1e30f,-1e30f,-1e30f,-1e30f};
    #pragma unroll
    for (int jj = 0; jj < 2; ++jj) {
        int j = t + jj*256;
        float kk[16], kpv[12];
        const float4* kr = (const float4*)(kw + (size_t)j*16);
        *(float4*)&kk[0]=kr[0]; *(float4*)&kk[4]=kr[1]; *(float4*)&kk[8]=kr[2]; *(float4*)&kk[12]=kr[3];
        const float4* kpr = (const float4*)(kpw + (size_t)j*12);
        *(float4*)&kpv[0]=kpr[0]; *(float4*)&kpv[4]=kpr[1]; *(float4*)&kpv[8]=kpr[2];
        float mj = mask[j];
        #pragma unroll
        for (int qq = 0; qq < TI; ++qq) {
            float dot = 0.f;
            #pragma unroll
            for (int c = 0; c < 16; ++c) dot += sQ[qq][c]*kk[c];
            float sq = 0.f;
            #pragma unroll
            for (int e = 0; e < 12; ++e) { float d = sQP[qq][e]-kpv[e]; sq += d*d; }
            float bv = bbc[(size_t)(i0+qq)*NRIG + j];
            float lgt = dot*QKS + bv + hwv*sq + INF_*(sMi[qq]*mj - 1.0f);
            lg[jj][qq] = lgt;
            lmax[qq] = fmaxf(lmax[qq], lgt);
        }
    }
    #pragma unroll
    for (int sft = 1; sft < 64; sft <<= 1)
        #pragma unroll
        for (int qq=0;qq<TI;++qq) lmax[qq] = fmaxf(lmax[qq], __shfl_xor(lmax[qq], sft));
    if (lane == 0) { for (int qq=0;qq<TI;++qq) redM[qq][wid] = lmax[qq]; }
    __syncthreads();
    float M[TI], psum[TI];
    #pragma unroll
    for (int qq=0;qq<TI;++qq) {
        M[qq] = fmaxf(fmaxf(redM[qq][0],redM[qq][1]),fmaxf(redM[qq][2],redM[qq][3]));
        psum[qq]=0.f;
    }
    #pragma unroll
    for (int jj = 0; jj < 2; ++jj) {
        int j = t + jj*256;
        #pragma unroll
        for (int qq=0;qq<TI;++qq) {
            float e = __expf(lg[jj][qq] - M[qq]);
            sE[qq][j] = e;
            psum[qq] += e;
        }
    }
    #pragma unroll
    for (int sft = 1; sft < 64; sft <<= 1)
        #pragma unroll
        for (int qq=0;qq<TI;++qq) psum[qq] += __shfl_xor(psum[qq], sft);
    if (lane == 0) { for (int qq=0;qq<TI;++qq) redS[qq][wid] = psum[qq]; }
    __syncthreads();

    {
        const int c0 = wid*10;
        float acc[10][TI];
        #pragma unroll
        for (int ci=0;ci<10;++ci)
            #pragma unroll
            for (int qq=0;qq<TI;++qq) acc[ci][qq]=0.f;

        #pragma unroll
        for (int m = 0; m < 8; ++m) {
            const int j = lane + 64*m;
            float ev[TI];
            #pragma unroll
            for (int qq=0;qq<TI;++qq) ev[qq] = sE[qq][j];
            #pragma unroll
            for (int ci = 0; ci < 10; ++ci) {
                float vv = vt[(size_t)(c0+ci)*NRIG + j];
                #pragma unroll
                for (int qq=0;qq<TI;++qq) acc[ci][qq] += ev[qq]*vv;
            }
        }
        #pragma unroll
        for (int ci=0;ci<10;++ci)
            #pragma unroll
            for (int qq=0;qq<TI;++qq) {
                acc[ci][qq] += __shfl_xor(acc[ci][qq], 1);
                acc[ci][qq] += __shfl_xor(acc[ci][qq], 2);
            }
        if ((lane & 3) == 0) {
            const int g = lane >> 2;
            #pragma unroll
            for (int qq=0;qq<TI;++qq)
                #pragma unroll
                for (int ci=0;ci<10;++ci)
                    sP[qq][g][c0+ci] = acc[ci][qq];
        }
    }
    __syncthreads();

    if (t < TI*41) {
        const int qq = t / 41, c = t % 41;
        const int n = i0 + qq;
        float S = redS[qq][0]+redS[qq][1]+redS[qq][2]+redS[qq][3];
        float Sinv = 1.0f / S;
        if (c == 40) {
            (ws + OFF_RS)[(size_t)n*NH + h] = S * Sinv;
        } else {
            float acc = 0.f;
            #pragma unroll
            for (int g = 0; g < 16; ++g) acc += sP[qq][g][c];
            acc *= Sinv;
            if (c < 16) (ws + OFF_O  )[((size_t)n*NH + h)*CH + c]      = acc;
            else        (ws + OFF_OPT)[((size_t)n*NH + h)*24 + (c-16)] = acc;
        }
    }
}

// =====================================================================
// Kernel D1: build feats F[512][960] (o | o_pt xyz | norm | o_pair)
// block = 4 rigids, 256 threads. grid = 128.
// =====================================================================
__global__ __launch_bounds__(256) void feats_kernel(
    const float* __restrict__ rot, const float* __restrict__ trans,
    float* __restrict__ ws)
{
    constexpr int TI = 4;
    const int i0 = blockIdx.x*TI;
    const int t  = threadIdx.x;
    float* F = ws + OFF_F;
    const float* o_ws = ws + OFF_O;  const float* optg = ws + OFF_OPT;
    const float* rs   = ws + OFF_RS; const float* pz   = ws + OFF_PZ;

    for (int e = t; e < TI*HC; e += 256) {
        int qq = e/HC, c = e%HC;
        F[(size_t)(i0+qq)*960 + c] = o_ws[(size_t)(i0+qq)*HC + c];
    }
    for (int e = t; e < TI*96; e += 256) {
        int qq = e/96, hp = e%96; int n = i0+qq;
        const float* g = optg + ((size_t)n*NH + hp/PV)*24 + (hp%PV)*3;
        float gx = g[0]-trans[n*3+0], gy = g[1]-trans[n*3+1], gz = g[2]-trans[n*3+2];
        const float* R = rot + (size_t)n*9;
        float lx = R[0]*gx + R[3]*gy + R[6]*gz;   // rot^T
        float ly = R[1]*gx + R[4]*gy + R[7]*gz;
        float lz = R[2]*gx + R[5]*gy + R[8]*gz;
        float* Fr = F + (size_t)n*960;
        Fr[192+hp] = lx; Fr[288+hp] = ly; Fr[384+hp] = lz;
        Fr[480+hp] = sqrtf(lx*lx+ly*ly+lz*lz + 1e-8f);
    }
    for (int e = t; e < TI*384; e += 256) {
        int qq = e/384, hd = e%384; int n = i0+qq;
        F[(size_t)n*960 + 576 + hd] = rs[(size_t)n*NH + hd/32] * pz[(size_t)n*32 + (hd%32)];
    }
}

// =====================================================================
// Kernel D2: tiled GEMM  out[512][384] = F[512][960] @ w_out + b_out
// same template as proj_gemm. grid = 8 x 12 = 96.
// =====================================================================
__global__ __launch_bounds__(256) void out_gemm_kernel(
    const float* __restrict__ w_out, const float* __restrict__ b_out,
    const float* __restrict__ ws, float* __restrict__ out)
{
    constexpr int BM=64, BN=32, BK=32, LDA=68;
    __shared__ float sA[BK][LDA];
    __shared__ float sB[BK][BN];
    const float* F = ws + OFF_F;
    const int m0 = blockIdx.x * BM;
    const int c0 = blockIdx.y * BN;
    const int t  = threadIdx.x;
    const int tx = t & 15, ty = t >> 4;

    float acc[4][2] = {};

    for (int kt = 0; kt < 960/BK; ++kt) {
        const int k0 = kt*BK;
        #pragma unroll
        for (int r = 0; r < 2; ++r) {
            int qd = r*256 + t;
            int m = qd >> 3, kq = (qd & 7) << 2;
            float4 f = *(const float4*)(F + (size_t)(m0+m)*960 + k0 + kq);
            sA[kq+0][m] = f.x; sA[kq+1][m] = f.y;
            sA[kq+2][m] = f.z; sA[kq+3][m] = f.w;
        }
        {
            int kk = t >> 3, c4 = (t & 7) << 2;
            float4 f = *(const float4*)(w_out + (size_t)(k0+kk)*CS + c0 + c4);
            *(float4*)&sB[kk][c4] = f;
        }
        __syncthreads();
        #pragma unroll
        for (int kk = 0; kk < BK; ++kk) {
            float4 a = *(const float4*)&sA[kk][ty*4];
            float2 b = *(const float2*)&sB[kk][tx*2];
            acc[0][0] += a.x*b.x; acc[0][1] += a.x*b.y;
            acc[1][0] += a.y*b.x; acc[1][1] += a.y*b.y;
            acc[2][0] += a.z*b.x; acc[2][1] += a.z*b.y;
            acc[3][0] += a.w*b.x; acc[3][1] += a.w*b.y;
        }
        __syncthreads();
    }

    #pragma unroll
    for (int i = 0; i < 4; ++i)
        #pragma unroll
        for (int j = 0; j < 2; ++j) {
            int n = m0 + ty*4 + i;
            int c = c0 + tx*2 + j;
            out[(size_t)n*CS + c] = acc[i][j] + b_out[c];
        }
}

// =====================================================================
extern "C" void kernel_launch(void* const* d_in, const int* in_sizes, int n_in,
                              void* d_out, int out_size, void* d_ws, size_t ws_size,
                              hipStream_t stream)
{
    const float* s     = (const float*)d_in[0];
    const float* z     = (const float*)d_in[1];
    const float* rot   = (const float*)d_in[2];
    const float* trans = (const float*)d_in[3];
    const float* mask  = (const float*)d_in[4];
    const int*   ridx  = (const int*)  d_in[5];
    const float* wq    = (const float*)d_in[6];
    const float* bq    = (const float*)d_in[7];
    const float* wkv   = (const float*)d_in[8];
    const float* bkv   = (const float*)d_in[9];
    const float* wqp   = (const float*)d_in[10];
    const float* bqp   = (const float*)d_in[11];
    const float* wkvp  = (const float*)d_in[12];
    const float* bkvp  = (const float*)d_in[13];
    const float* wb    = (const float*)d_in[14];
    const float* bb    = (const float*)d_in[15];
    const float* wdz   = (const float*)d_in[16];
    const float* bdz   = (const float*)d_in[17];
    const float* hw    = (const float*)d_in[18];
    const float* wout  = (const float*)d_in[19];
    const float* bout  = (const float*)d_in[20];
    float* ws  = (float*)d_ws;
    float* out = (float*)d_out;

    hipLaunchKernelGGL(proj_gemm_kernel, dim3(NRIG/64, 1152/32), dim3(256), 0, stream,
        s, wq,bq, wkv,bkv, wqp,bqp, wkvp,bkvp, ws);
    hipLaunchKernelGGL(rotate_kernel, dim3(NRIG*192/256), dim3(256), 0, stream,
        rot, trans, ws);
    hipLaunchKernelGGL(bpair_kernel, dim3(NRIG), dim3(256), 0, stream,
        z, ridx, wb, bb, wdz, bdz, ws);
    hipLaunchKernelGGL(attn_kernel, dim3(NH, NRIG/4), dim3(256), 0, stream,
        hw, mask, ws);
    hipLaunchKernelGGL(feats_kernel, dim3(NRIG/4), dim3(256), 0, stream,
        rot, trans, ws);
    hipLaunchKernelGGL(out_gemm_kernel, dim3(NRIG/64, CS/32), dim3(256), 0, stream,
        wout, bout, ws, out);
}